// Round 2
// baseline (1059.313 us; speedup 1.0000x reference)
//
#include <hip/hip_runtime.h>
#include <math.h>

#define H 128

__device__ __forceinline__ float fast_tanh(float v) {
    // tanh(v) = 1 - 2/(exp(2v)+1); exact at +-inf saturation
    float e = __expf(2.0f * v);
    float r = __builtin_amdgcn_rcpf(e + 1.0f);
    return fmaf(-2.0f, r, 1.0f);
}

// s[i] = tanh(x[i,:] @ w1 + b1) @ w2 + b2
// one block per 64-row tile; 256 threads; thread = (tr 0..7 rows, tc 0..31 col4s)
__global__ __launch_bounds__(256, 3) void k_compute_s(
    const float* __restrict__ x, const float* __restrict__ w1,
    const float* __restrict__ b1, const float* __restrict__ w2,
    const float* __restrict__ b2, float* __restrict__ s, int n)
{
    __shared__ float xs[64 * H];   // 32 KB: x tile
    __shared__ float w1c[32 * H];  // 16 KB: w1 k-chunk
    const int tid = threadIdx.x;
    const int tr = tid >> 5;   // row group (8 rows each)
    const int tc = tid & 31;   // col group (4 cols each)
    const long long row0 = (long long)blockIdx.x * 64;

    // stage x tile: 8192 contiguous floats, fully coalesced float4
    {
        const float4* xg4 = (const float4*)x;
        float4* xsv = (float4*)xs;
        const long long lim = (long long)n * (H / 4);
        #pragma unroll
        for (int i = 0; i < 8; ++i) {
            int idx = tid + i * 256;
            long long g = row0 * (H / 4) + idx;
            float4 v = {0.f, 0.f, 0.f, 0.f};
            if (g < lim) v = xg4[g];
            xsv[idx] = v;
        }
    }

    float4 acc[8];
    #pragma unroll
    for (int i = 0; i < 8; ++i) acc[i] = {0.f, 0.f, 0.f, 0.f};

    for (int c = 0; c < 4; ++c) {
        __syncthreads();
        // load w1 rows [32c, 32c+32): 4096 floats
        {
            const float4* wg = (const float4*)(w1 + 32 * c * H);
            float4* wv4 = (float4*)w1c;
            #pragma unroll
            for (int i = 0; i < 4; ++i) wv4[tid + i * 256] = wg[tid + i * 256];
        }
        __syncthreads();
        const int kbase = 32 * c;  // global k offset into the x tile (bug fix)
        #pragma unroll 2
        for (int k = 0; k < 32; k += 4) {
            float4 xv[8];
            #pragma unroll
            for (int i = 0; i < 8; ++i)
                xv[i] = *(const float4*)&xs[(8 * tr + i) * H + kbase + k];
            float4 wv[4];
            #pragma unroll
            for (int kk = 0; kk < 4; ++kk)
                wv[kk] = *(const float4*)&w1c[(k + kk) * H + 4 * tc];
            #pragma unroll
            for (int i = 0; i < 8; ++i) {
                acc[i].x = fmaf(xv[i].x, wv[0].x, acc[i].x);
                acc[i].y = fmaf(xv[i].x, wv[0].y, acc[i].y);
                acc[i].z = fmaf(xv[i].x, wv[0].z, acc[i].z);
                acc[i].w = fmaf(xv[i].x, wv[0].w, acc[i].w);
                acc[i].x = fmaf(xv[i].y, wv[1].x, acc[i].x);
                acc[i].y = fmaf(xv[i].y, wv[1].y, acc[i].y);
                acc[i].z = fmaf(xv[i].y, wv[1].z, acc[i].z);
                acc[i].w = fmaf(xv[i].y, wv[1].w, acc[i].w);
                acc[i].x = fmaf(xv[i].z, wv[2].x, acc[i].x);
                acc[i].y = fmaf(xv[i].z, wv[2].y, acc[i].y);
                acc[i].z = fmaf(xv[i].z, wv[2].z, acc[i].z);
                acc[i].w = fmaf(xv[i].z, wv[2].w, acc[i].w);
                acc[i].x = fmaf(xv[i].w, wv[3].x, acc[i].x);
                acc[i].y = fmaf(xv[i].w, wv[3].y, acc[i].y);
                acc[i].z = fmaf(xv[i].w, wv[3].z, acc[i].z);
                acc[i].w = fmaf(xv[i].w, wv[3].w, acc[i].w);
            }
        }
    }

    // epilogue: h = tanh(acc + b1); partial s = h . w2; reduce over 32 col-threads
    const float4 b1v = ((const float4*)b1)[tc];
    const float4 w2v = ((const float4*)w2)[tc];
    const float b2v = b2[0];
    float res[8];
    #pragma unroll
    for (int i = 0; i < 8; ++i) {
        float hx = fast_tanh(acc[i].x + b1v.x);
        float hy = fast_tanh(acc[i].y + b1v.y);
        float hz = fast_tanh(acc[i].z + b1v.z);
        float hw = fast_tanh(acc[i].w + b1v.w);
        res[i] = hx * w2v.x + hy * w2v.y + hz * w2v.z + hw * w2v.w;
    }
    #pragma unroll
    for (int off = 16; off; off >>= 1) {
        #pragma unroll
        for (int i = 0; i < 8; ++i) res[i] += __shfl_xor(res[i], off);
    }
    if (tc == 0) {
        #pragma unroll
        for (int i = 0; i < 8; ++i) {
            long long r = row0 + 8 * tr + i;
            if (r < n) s[r] = res[i] + b2v;
        }
    }
}

// offs[g] = first index i with batch[i] >= g (batch sorted); g in [0, G]
// Handles both int32 and int64 batch: if the int32 word at [n-1] is 0, the
// array must be little-endian int64 (a sorted batch ending in 0 => all zero,
// prob ~0), so element i lives at word 2*i (low word; values < 2^31).
__global__ void k_offsets(const int* __restrict__ batch, int n, int g_count,
                          int* __restrict__ offs)
{
    int g = blockIdx.x * blockDim.x + threadIdx.x;
    if (g > g_count) return;
    const bool is64 = (batch[n - 1] == 0);
    int lo = 0, hi = n;
    while (lo < hi) {
        int mid = (lo + hi) >> 1;
        int v = is64 ? batch[2 * mid] : batch[mid];
        if (v < g) lo = mid + 1; else hi = mid;
    }
    offs[g] = lo;
}

// per-graph max and 1/denom (one wave per graph)
__global__ void k_stats(const float* __restrict__ s, const int* __restrict__ offs,
                        float* __restrict__ smax, float* __restrict__ sinv)
{
    const int g = blockIdx.x;
    const int lane = threadIdx.x;  // 64
    const int start = offs[g], end = offs[g + 1];
    float m = -INFINITY;
    for (int i = start + lane; i < end; i += 64) m = fmaxf(m, s[i]);
    #pragma unroll
    for (int off = 32; off; off >>= 1) m = fmaxf(m, __shfl_xor(m, off));
    if (!(m >= -3.0e38f)) m = 0.0f;  // empty graph guard (matches reference)
    float d = 0.0f;
    for (int i = start + lane; i < end; i += 64) d += __expf(s[i] - m);
    #pragma unroll
    for (int off = 32; off; off >>= 1) d += __shfl_xor(d, off);
    if (lane == 0) {
        smax[g] = m;
        sinv[g] = (d > 0.0f) ? (1.0f / d) : 1.0f;  // matches reference denom guard
    }
}

// pooled[g,:] = sum_i w_i * x[i,:]; one block per graph; 8 rows in flight
__global__ __launch_bounds__(256) void k_pool(
    const float* __restrict__ x, const float* __restrict__ s,
    const int* __restrict__ offs, const float* __restrict__ smax,
    const float* __restrict__ sinv, float* __restrict__ out)
{
    const int g = blockIdx.x;
    const int tid = threadIdx.x;
    const int rr = tid >> 5;  // 0..7 row offset
    const int c4 = tid & 31;  // float4 column
    const int start = offs[g], end = offs[g + 1];
    const float m = smax[g];
    const float inv = sinv[g];
    float4 acc = {0.f, 0.f, 0.f, 0.f};
    for (int i = start + rr; i < end; i += 8) {
        float w = __expf(s[i] - m) * inv;
        float4 xv = ((const float4*)(x + (size_t)i * H))[c4];
        acc.x = fmaf(w, xv.x, acc.x);
        acc.y = fmaf(w, xv.y, acc.y);
        acc.z = fmaf(w, xv.z, acc.z);
        acc.w = fmaf(w, xv.w, acc.w);
    }
    __shared__ float4 red[8][32];
    red[rr][c4] = acc;
    __syncthreads();
    if (rr == 0) {
        float4 t = red[0][c4];
        #pragma unroll
        for (int j = 1; j < 8; ++j) {
            float4 u = red[j][c4];
            t.x += u.x; t.y += u.y; t.z += u.z; t.w += u.w;
        }
        ((float4*)(out + (size_t)g * H))[c4] = t;
    }
}

extern "C" void kernel_launch(void* const* d_in, const int* in_sizes, int n_in,
                              void* d_out, int out_size, void* d_ws, size_t ws_size,
                              hipStream_t stream)
{
    const float* x     = (const float*)d_in[0];
    const int*   batch = (const int*)d_in[1];
    const float* w1    = (const float*)d_in[2];
    const float* b1    = (const float*)d_in[3];
    const float* w2    = (const float*)d_in[4];
    const float* b2    = (const float*)d_in[5];
    const int n = in_sizes[0] / H;       // 1e6 rows (robust to batch dtype width)
    const int G = out_size / H;          // 4096 graphs
    float* out = (float*)d_out;

    // workspace layout: s[n] | smax[G] | sinv[G] | offs[G+1]
    float* s    = (float*)d_ws;
    float* smax = s + n;
    float* sinv = smax + G;
    int*   offs = (int*)(sinv + G);

    const int tiles = (n + 63) / 64;
    k_compute_s<<<tiles, 256, 0, stream>>>(x, w1, b1, w2, b2, s, n);
    k_offsets<<<(G + 1 + 255) / 256, 256, 0, stream>>>(batch, n, G, offs);
    k_stats<<<G, 64, 0, stream>>>(s, offs, smax, sinv);
    k_pool<<<G, 256, 0, stream>>>(x, s, offs, smax, sinv, out);
}

// Round 3
// 1028.516 us; speedup vs baseline: 1.0299x; 1.0299x over previous
//
#include <hip/hip_runtime.h>
#include <math.h>

#define H 128

typedef float f32x4 __attribute__((ext_vector_type(4)));
typedef __bf16 bf16x8 __attribute__((ext_vector_type(8)));

__device__ __forceinline__ float fast_tanh(float v) {
    // tanh(v) = 1 - 2/(exp(2v)+1); exact at +-inf saturation
    float e = __expf(2.0f * v);
    float r = __builtin_amdgcn_rcpf(e + 1.0f);
    return fmaf(-2.0f, r, 1.0f);
}

// s[i] = tanh(x[i,:] @ w1 + b1) @ w2 + b2  via split-bf16 MFMA:
//   x@w ~= xh@wh + xl@wh + xh@wl  (each term one mfma_f32_16x16x32_bf16 chain)
// Block = 256 threads (4 waves). Per tile: 128 rows; wave owns 32 rows (2 M-tiles).
// w1^T staged once per block into LDS as bf16 hi/lo, 16B-chunk XOR swizzle.
__global__ __launch_bounds__(256, 2) void k_compute_s_mfma(
    const float* __restrict__ x, const float* __restrict__ w1,
    const float* __restrict__ b1, const float* __restrict__ w2,
    const float* __restrict__ b2, float* __restrict__ s, int n, int ntiles)
{
    __shared__ __bf16 wsm[2 * H * H];  // [hi|lo][n][k swizzled] = 64 KB exactly

    const int tid = threadIdx.x;

    // ---- stage w1 (k-major [k][n]) -> LDS transposed [n][k], bf16 hi/lo ----
    for (int idx = tid; idx < H * H; idx += 256) {
        int k = idx >> 7, nn = idx & 127;      // w1[k][nn], coalesced in nn
        float v = w1[idx];
        __bf16 h = (__bf16)v;
        __bf16 l = (__bf16)(v - (float)h);
        int c = (k >> 3) ^ (nn & 15);          // 16B-chunk XOR swizzle
        int pos = nn * H + c * 8 + (k & 7);
        wsm[pos] = h;
        wsm[H * H + pos] = l;
    }

    const int wv = tid >> 6;       // wave 0..3
    const int lane = tid & 63;
    const int p = lane & 15;       // A: m-row / B: n-col / D: col
    const int q = lane >> 4;       // A,B: k-group / D: row-group

    // per-lane epilogue constants: b1/w2 at col nt*16+p
    float b1v[8], w2v[8];
    #pragma unroll
    for (int nt = 0; nt < 8; ++nt) {
        b1v[nt] = b1[nt * 16 + p];
        w2v[nt] = w2[nt * 16 + p];
    }
    const float b2v = b2[0];

    __syncthreads();  // weights ready; read-only below -> no more barriers

    for (int tile = blockIdx.x; tile < ntiles; tile += (int)gridDim.x) {
        const long long base = (long long)tile * 128 + wv * 32;

        // ---- load 2 M-tiles of x direct from global, split to bf16 hi/lo ----
        bf16x8 ah[2][4], al[2][4];
        #pragma unroll
        for (int mt = 0; mt < 2; ++mt) {
            long long r = base + mt * 16 + p;
            const float4* rp = (const float4*)(x + r * H);
            const bool ok = (r < (long long)n);
            #pragma unroll
            for (int kc = 0; kc < 4; ++kc) {
                float4 u0 = {0.f, 0.f, 0.f, 0.f}, u1 = {0.f, 0.f, 0.f, 0.f};
                if (ok) { u0 = rp[kc * 8 + q * 2]; u1 = rp[kc * 8 + q * 2 + 1]; }
                float vals[8] = {u0.x, u0.y, u0.z, u0.w, u1.x, u1.y, u1.z, u1.w};
                #pragma unroll
                for (int j = 0; j < 8; ++j) {
                    __bf16 h = (__bf16)vals[j];
                    ah[mt][kc][j] = h;
                    al[mt][kc][j] = (__bf16)(vals[j] - (float)h);
                }
            }
        }

        // ---- MFMA main: acc[mt][nt] over 4 K-chunks, 3-term split ----
        f32x4 acc[2][8];
        #pragma unroll
        for (int mt = 0; mt < 2; ++mt)
            #pragma unroll
            for (int nt = 0; nt < 8; ++nt)
                acc[mt][nt] = (f32x4){0.f, 0.f, 0.f, 0.f};

        #pragma unroll
        for (int nt = 0; nt < 8; ++nt) {
            const int nn = nt * 16 + p;
            #pragma unroll
            for (int kc = 0; kc < 4; ++kc) {
                const int c = (kc * 4 + q) ^ p;  // undo swizzle (nn&15 == p)
                const __bf16* bb = &wsm[nn * H + c * 8];
                bf16x8 bh = *(const bf16x8*)bb;
                bf16x8 bl = *(const bf16x8*)(bb + H * H);
                acc[0][nt] = __builtin_amdgcn_mfma_f32_16x16x32_bf16(ah[0][kc], bh, acc[0][nt], 0, 0, 0);
                acc[1][nt] = __builtin_amdgcn_mfma_f32_16x16x32_bf16(ah[1][kc], bh, acc[1][nt], 0, 0, 0);
                acc[0][nt] = __builtin_amdgcn_mfma_f32_16x16x32_bf16(al[0][kc], bh, acc[0][nt], 0, 0, 0);
                acc[1][nt] = __builtin_amdgcn_mfma_f32_16x16x32_bf16(al[1][kc], bh, acc[1][nt], 0, 0, 0);
                acc[0][nt] = __builtin_amdgcn_mfma_f32_16x16x32_bf16(ah[0][kc], bl, acc[0][nt], 0, 0, 0);
                acc[1][nt] = __builtin_amdgcn_mfma_f32_16x16x32_bf16(ah[1][kc], bl, acc[1][nt], 0, 0, 0);
            }
        }

        // ---- epilogue: s[row] = sum_col tanh(C+b1)*w2 + b2 ----
        #pragma unroll
        for (int mt = 0; mt < 2; ++mt) {
            float part[4] = {0.f, 0.f, 0.f, 0.f};
            #pragma unroll
            for (int nt = 0; nt < 8; ++nt) {
                #pragma unroll
                for (int rg = 0; rg < 4; ++rg) {
                    float hv = fast_tanh(acc[mt][nt][rg] + b1v[nt]);
                    part[rg] = fmaf(hv, w2v[nt], part[rg]);
                }
            }
            #pragma unroll
            for (int off = 1; off < 16; off <<= 1) {
                #pragma unroll
                for (int rg = 0; rg < 4; ++rg)
                    part[rg] += __shfl_xor(part[rg], off);
            }
            if (p == 0) {
                #pragma unroll
                for (int rg = 0; rg < 4; ++rg) {
                    long long row = base + mt * 16 + q * 4 + rg;
                    if (row < (long long)n) s[row] = part[rg] + b2v;
                }
            }
        }
    }
}

// offs[g] = first index i with batch[i] >= g (batch sorted); g in [0, G]
// Handles int32 or int64 batch (see R1 note): sorted batch ending in word 0
// implies int64 little-endian; values < 2^31 so low word suffices.
__global__ void k_offsets(const int* __restrict__ batch, int n, int g_count,
                          int* __restrict__ offs)
{
    int g = blockIdx.x * blockDim.x + threadIdx.x;
    if (g > g_count) return;
    const bool is64 = (batch[n - 1] == 0);
    int lo = 0, hi = n;
    while (lo < hi) {
        int mid = (lo + hi) >> 1;
        int v = is64 ? batch[2 * mid] : batch[mid];
        if (v < g) lo = mid + 1; else hi = mid;
    }
    offs[g] = lo;
}

// per-graph max and 1/denom (one wave per graph)
__global__ void k_stats(const float* __restrict__ s, const int* __restrict__ offs,
                        float* __restrict__ smax, float* __restrict__ sinv)
{
    const int g = blockIdx.x;
    const int lane = threadIdx.x;  // 64
    const int start = offs[g], end = offs[g + 1];
    float m = -INFINITY;
    for (int i = start + lane; i < end; i += 64) m = fmaxf(m, s[i]);
    #pragma unroll
    for (int off = 32; off; off >>= 1) m = fmaxf(m, __shfl_xor(m, off));
    if (!(m >= -3.0e38f)) m = 0.0f;  // empty graph guard (matches reference)
    float d = 0.0f;
    for (int i = start + lane; i < end; i += 64) d += __expf(s[i] - m);
    #pragma unroll
    for (int off = 32; off; off >>= 1) d += __shfl_xor(d, off);
    if (lane == 0) {
        smax[g] = m;
        sinv[g] = (d > 0.0f) ? (1.0f / d) : 1.0f;  // matches reference denom guard
    }
}

// pooled[g,:] = sum_i w_i * x[i,:]; one block per graph; 8 rows in flight
__global__ __launch_bounds__(256) void k_pool(
    const float* __restrict__ x, const float* __restrict__ s,
    const int* __restrict__ offs, const float* __restrict__ smax,
    const float* __restrict__ sinv, float* __restrict__ out)
{
    const int g = blockIdx.x;
    const int tid = threadIdx.x;
    const int rr = tid >> 5;  // 0..7 row offset
    const int c4 = tid & 31;  // float4 column
    const int start = offs[g], end = offs[g + 1];
    const float m = smax[g];
    const float inv = sinv[g];
    float4 acc = {0.f, 0.f, 0.f, 0.f};
    for (int i = start + rr; i < end; i += 8) {
        float w = __expf(s[i] - m) * inv;
        float4 xv = ((const float4*)(x + (size_t)i * H))[c4];
        acc.x = fmaf(w, xv.x, acc.x);
        acc.y = fmaf(w, xv.y, acc.y);
        acc.z = fmaf(w, xv.z, acc.z);
        acc.w = fmaf(w, xv.w, acc.w);
    }
    __shared__ float4 red[8][32];
    red[rr][c4] = acc;
    __syncthreads();
    if (rr == 0) {
        float4 t = red[0][c4];
        #pragma unroll
        for (int j = 1; j < 8; ++j) {
            float4 u = red[j][c4];
            t.x += u.x; t.y += u.y; t.z += u.z; t.w += u.w;
        }
        ((float4*)(out + (size_t)g * H))[c4] = t;
    }
}

extern "C" void kernel_launch(void* const* d_in, const int* in_sizes, int n_in,
                              void* d_out, int out_size, void* d_ws, size_t ws_size,
                              hipStream_t stream)
{
    const float* x     = (const float*)d_in[0];
    const int*   batch = (const int*)d_in[1];
    const float* w1    = (const float*)d_in[2];
    const float* b1    = (const float*)d_in[3];
    const float* w2    = (const float*)d_in[4];
    const float* b2    = (const float*)d_in[5];
    const int n = in_sizes[0] / H;       // 1e6 rows
    const int G = out_size / H;          // 4096 graphs
    float* out = (float*)d_out;

    // workspace layout: s[n] | smax[G] | sinv[G] | offs[G+1]
    float* s    = (float*)d_ws;
    float* smax = s + n;
    float* sinv = smax + G;
    int*   offs = (int*)(sinv + G);

    const int tiles = (n + 127) / 128;
    k_compute_s_mfma<<<1024, 256, 0, stream>>>(x, w1, b1, w2, b2, s, n, tiles);
    k_offsets<<<(G + 1 + 255) / 256, 256, 0, stream>>>(batch, n, G, offs);
    k_stats<<<G, 64, 0, stream>>>(s, offs, smax, sinv);
    k_pool<<<G, 256, 0, stream>>>(x, s, offs, smax, sinv, out);
}